// Round 6
// baseline (164.055 us; speedup 1.0000x reference)
//
#include <hip/hip_runtime.h>

// Problem constants
#define BATCH 8192
#define INF_  1024   // IN
#define OUTF  1024   // OUT
#define INV_B (1.0f/8192.0f)
#define RATE_C 1e-3f
#define SPLITZ 16    // GEMM2 split-K factor (bf16 partials)

typedef __bf16 bf16x8 __attribute__((ext_vector_type(8)));
typedef float  f32x4  __attribute__((ext_vector_type(4)));
typedef const __attribute__((address_space(1))) unsigned int* gas_t;
typedef __attribute__((address_space(3))) unsigned int* las_t;

// fp32 -> bf16 round-to-nearest-even
static __device__ __forceinline__ unsigned short f2bf(float f) {
  unsigned int u = __float_as_uint(f);
  u += 0x7fffu + ((u >> 16) & 1u);
  return (unsigned short)(u >> 16);
}
static __device__ __forceinline__ float bf2f(unsigned short h) {
  return __uint_as_float(((unsigned int)h) << 16);
}

// ---------------------------------------------------------------------------
// Kernel 1 (merged): blocks [0,2048): x -> xb (bf16) + xT (bf16, transposed)
//                    blocks [2048,3072): W row -> Wb + rate[o]
// ---------------------------------------------------------------------------
__global__ __launch_bounds__(256) void k_convert(
    const float* __restrict__ x, unsigned short* __restrict__ xb,
    unsigned short* __restrict__ xT, const float* __restrict__ W,
    unsigned short* __restrict__ Wb, float* __restrict__ rate) {
  const int t = threadIdx.x;
  if (blockIdx.x >= 2048) {
    __shared__ float red[256];
    const int o = blockIdx.x - 2048;
    float4 v = *(const float4*)&W[(size_t)o * INF_ + t * 4];
    ushort4 h;
    h.x = f2bf(v.x); h.y = f2bf(v.y); h.z = f2bf(v.z); h.w = f2bf(v.w);
    *(ushort4*)&Wb[(size_t)o * INF_ + t * 4] = h;
    red[t] = v.x * v.x + v.y * v.y + v.z * v.z + v.w * v.w;
    __syncthreads();
    for (int s = 128; s > 0; s >>= 1) {
      if (t < s) red[t] += red[t + s];
      __syncthreads();
    }
    if (t == 0) {
      float nrm = sqrtf(red[0]);
      rate[o] = RATE_C * sqrtf(fabsf(1.0f - nrm));
    }
    return;
  }
  // ---- x convert + transpose (64x64 tile), packed-u32 LDS ----
  __shared__ unsigned int t32[64][33];
  const int bx = blockIdx.x & 15;
  const int by = blockIdx.x >> 4;
  const int r0 = by * 64;
  const int c0 = bx * 64;
  const int m = t & 15;
  const int q = t >> 4;
#pragma unroll
  for (int p = 0; p < 2; ++p) {
    const int r2 = p * 16 + q;
    const int b  = r0 + 2 * r2;
    float4 v0 = *(const float4*)&x[(size_t)b * INF_ + c0 + 4 * m];
    float4 v1 = *(const float4*)&x[(size_t)(b + 1) * INF_ + c0 + 4 * m];
    ushort4 h0, h1;
    h0.x = f2bf(v0.x); h0.y = f2bf(v0.y); h0.z = f2bf(v0.z); h0.w = f2bf(v0.w);
    h1.x = f2bf(v1.x); h1.y = f2bf(v1.y); h1.z = f2bf(v1.z); h1.w = f2bf(v1.w);
    *(ushort4*)&xb[(size_t)b * INF_ + c0 + 4 * m] = h0;
    *(ushort4*)&xb[(size_t)(b + 1) * INF_ + c0 + 4 * m] = h1;
    t32[4 * m + 0][r2] = (unsigned int)h0.x | ((unsigned int)h1.x << 16);
    t32[4 * m + 1][r2] = (unsigned int)h0.y | ((unsigned int)h1.y << 16);
    t32[4 * m + 2][r2] = (unsigned int)h0.z | ((unsigned int)h1.z << 16);
    t32[4 * m + 3][r2] = (unsigned int)h0.w | ((unsigned int)h1.w << 16);
  }
  __syncthreads();
  const int c  = t >> 2;
  const int sg = t & 3;
  unsigned int vb[8];
#pragma unroll
  for (int k = 0; k < 8; ++k) vb[k] = t32[c][sg * 8 + k];
  unsigned short* dst = &xT[(size_t)(c0 + c) * BATCH + r0 + sg * 16];
  *(uint4*)&dst[0] = make_uint4(vb[0], vb[1], vb[2], vb[3]);
  *(uint4*)&dst[8] = make_uint4(vb[4], vb[5], vb[6], vb[7]);
}

// ---------------------------------------------------------------------------
// Kernel 2/4: NT bf16 GEMM, 128x128 tile, BK=64, global_load_lds width=16
// staging + XOR chunk swizzle. XCD-aware 1-D grids.
//   mode 0 (GEMM1, 512 blocks): bf16 C (= u) with bias.
//   mode 1 (GEMM2, 1024 blocks): bf16 partial K-slices.
// ---------------------------------------------------------------------------
__global__ __launch_bounds__(256, 3) void k_gemm(
    const unsigned short* __restrict__ A, const unsigned short* __restrict__ B,
    int lda, int ldb, int kChunk, void* __restrict__ C, int ldc,
    const float* __restrict__ bias, int mode) {
  __shared__ unsigned short As[128 * 64];
  __shared__ unsigned short Bs[128 * 64];
  const int t  = threadIdx.x;
  const int id = blockIdx.x;
  int bx, by, bz;
  if (mode == 0) {
    by = (id & 7) | ((id >> 6) << 3);
    bx = (id >> 3) & 7;
    bz = 0;
  } else {
    bz = ((id & 7) << 1) | ((id >> 3) & 1);
    by = (id >> 4) & 7;
    bx = id >> 7;
  }
  const int m0   = by * 128;
  const int n0   = bx * 128;
  const int k0   = bz * kChunk;
  const int lane = t & 63;
  const int wave = t >> 6;
  const int sr   = lane >> 3;
  const int scx  = ((lane & 7) ^ sr) * 8;
  const int wm   = (wave >> 1) * 64;
  const int wn   = (wave & 1) * 64;
  const int fm   = lane & 15;
  const int fk   = (lane >> 4) * 8;

  f32x4 acc[4][4] = {};

  const int ldsRow0 = wave * 8;
  const size_t gArow = (size_t)(m0 + ldsRow0 + sr) * lda + scx;
  const size_t gBrow = (size_t)(n0 + ldsRow0 + sr) * ldb + scx;

  for (int ks = 0; ks < kChunk; ks += 64) {
    const int k = k0 + ks;
#pragma unroll
    for (int j = 0; j < 4; ++j) {
      __builtin_amdgcn_global_load_lds(
          (gas_t)&A[gArow + (size_t)j * 32 * lda + k],
          (las_t)&As[(ldsRow0 + j * 32) * 64], 16, 0, 0);
      __builtin_amdgcn_global_load_lds(
          (gas_t)&B[gBrow + (size_t)j * 32 * ldb + k],
          (las_t)&Bs[(ldsRow0 + j * 32) * 64], 16, 0, 0);
    }
    __syncthreads();
#pragma unroll
    for (int kk = 0; kk < 64; kk += 32) {
      bf16x8 af[4], bf[4];
      const int swz = ((((kk + fk) >> 3) ^ (fm & 7)) << 3);
#pragma unroll
      for (int i = 0; i < 4; ++i)
        af[i] = *(const bf16x8*)&As[(wm + i * 16 + fm) * 64 + swz];
#pragma unroll
      for (int i = 0; i < 4; ++i)
        bf[i] = *(const bf16x8*)&Bs[(wn + i * 16 + fm) * 64 + swz];
#pragma unroll
      for (int mt = 0; mt < 4; ++mt)
#pragma unroll
        for (int nt = 0; nt < 4; ++nt)
          acc[mt][nt] = __builtin_amdgcn_mfma_f32_16x16x32_bf16(
              af[mt], bf[nt], acc[mt][nt], 0, 0, 0);
    }
    __syncthreads();
  }

  // Epilogue. C/D layout (m89): col = lane&15, row = (lane>>4)*4 + reg
  const int er = (lane >> 4) * 4;
  if (mode == 0) {
    unsigned short* Cb = (unsigned short*)C;
#pragma unroll
    for (int nt = 0; nt < 4; ++nt) {
      const int n  = n0 + wn + nt * 16 + fm;
      const float bv = bias[n];
#pragma unroll
      for (int mt = 0; mt < 4; ++mt) {
        const int mb = m0 + wm + mt * 16 + er;
#pragma unroll
        for (int r = 0; r < 4; ++r)
          Cb[(size_t)(mb + r) * ldc + n] = f2bf(acc[mt][nt][r] + bv);
      }
    }
  } else {
    unsigned short* Cp = (unsigned short*)C + (size_t)bz * (1024u * 1024u);
#pragma unroll
    for (int nt = 0; nt < 4; ++nt) {
      const int n = n0 + wn + nt * 16 + fm;
#pragma unroll
      for (int mt = 0; mt < 4; ++mt) {
        const int mb = m0 + wm + mt * 16 + er;
#pragma unroll
        for (int r = 0; r < 4; ++r)
          Cp[(size_t)(mb + r) * ldc + n] = f2bf(acc[mt][nt][r]);
      }
    }
  }
}

// ---------------------------------------------------------------------------
// Kernel 3 (fused row_stats + yn): 256 blocks x 32 batch rows, wave-per-row
// (8 rows per wave, sequential). Per row: bf16 u read, butterfly max/argmax/
// sumexp, exact fp32 argmax repair (window 0.10), yn pack to swizzled LDS
// tile. Writeout: one thread per o writes the block's FULL 64 B batch-span
// of ynT row o (fixes R5's 32 B partial-sector scatter). Then in-block
// 4-wave spart reduction (tile LDS reused as float) -> spart[block][o].
// ---------------------------------------------------------------------------
__global__ __launch_bounds__(256, 2) void k_softhebb(
    const unsigned short* __restrict__ ub, const float* __restrict__ x,
    const float* __restrict__ W, unsigned short* __restrict__ ynT,
    float* __restrict__ s_part) {
  __shared__ unsigned short tile[32][1032];
  __shared__ int cands[4][32];
  __shared__ int cnt[4];
  const int t     = threadIdx.x;
  const int lane  = t & 63;
  const int wave  = t >> 6;
  const int b0    = blockIdx.x * 32;
  const int oBase = lane * 16;

  float sacc[16];
#pragma unroll
  for (int j = 0; j < 16; ++j) sacc[j] = 0.0f;

  for (int rw = 0; rw < 8; ++rw) {
    const int r = wave * 8 + rw;
    const int b = b0 + r;
    // load u row (bf16 -> fp32)
    float a[16];
    {
      uint4 q0 = *(const uint4*)&ub[(size_t)b * OUTF + oBase];
      uint4 q1 = *(const uint4*)&ub[(size_t)b * OUTF + oBase + 8];
      const unsigned int* qa = (const unsigned int*)&q0;
      const unsigned int* qb = (const unsigned int*)&q1;
#pragma unroll
      for (int c = 0; c < 4; ++c) {
        a[2 * c]     = __uint_as_float(qa[c] << 16);
        a[2 * c + 1] = __uint_as_float(qa[c] & 0xffff0000u);
        a[8 + 2 * c]     = __uint_as_float(qb[c] << 16);
        a[8 + 2 * c + 1] = __uint_as_float(qb[c] & 0xffff0000u);
      }
    }
    // max / argmax (first-index-wins)
    float mv = a[0]; int mi = oBase;
#pragma unroll
    for (int j = 1; j < 16; ++j)
      if (a[j] > mv) { mv = a[j]; mi = oBase + j; }
#pragma unroll
    for (int off = 1; off < 64; off <<= 1) {
      float ov = __shfl_xor(mv, off);
      int   oi = __shfl_xor(mi, off);
      if (ov > mv || (ov == mv && oi < mi)) { mv = ov; mi = oi; }
    }
    const float M = mv;
    float se = 0.0f;
#pragma unroll
    for (int j = 0; j < 16; ++j) se += __expf(a[j] - M);
#pragma unroll
    for (int off = 1; off < 64; off <<= 1) se += __shfl_xor(se, off);

    // candidates within window
    const float thr = M - 0.10f;
    unsigned int cflags = 0;
    int ccount = 0;
#pragma unroll
    for (int j = 0; j < 16; ++j)
      if (a[j] >= thr) { cflags |= (1u << j); ++ccount; }
    int tot = ccount;
#pragma unroll
    for (int off = 1; off < 64; off <<= 1) tot += __shfl_xor(tot, off);

    int best = mi;
    if (tot > 1) {
      if (lane == 0) cnt[wave] = 0;
      for (int j = 0; j < 16; ++j)
        if (cflags & (1u << j)) {
          int p = atomicAdd(&cnt[wave], 1);
          if (p < 32) cands[wave][p] = oBase + j;
        }
      int nc = cnt[wave]; if (nc > 32) nc = 32;
      float xr[16];
      const float* xp = &x[(size_t)b * INF_ + oBase];
#pragma unroll
      for (int j = 0; j < 16; j += 4) {
        float4 v = *(const float4*)&xp[j];
        xr[j] = v.x; xr[j + 1] = v.y; xr[j + 2] = v.z; xr[j + 3] = v.w;
      }
      float bv = -3.4e38f; int bi = 0x7fffffff;
      for (int c = 0; c < nc; ++c) {
        const int o = cands[wave][c];
        const float* wp = &W[(size_t)o * INF_ + oBase];
        float d = 0.0f;
#pragma unroll
        for (int j = 0; j < 16; j += 4) {
          float4 v = *(const float4*)&wp[j];
          d += xr[j] * v.x + xr[j + 1] * v.y + xr[j + 2] * v.z +
               xr[j + 3] * v.w;
        }
#pragma unroll
        for (int off = 1; off < 64; off <<= 1) d += __shfl_xor(d, off);
        if (d > bv || (d == bv && o < bi)) { bv = d; bi = o; }
      }
      best = bi;
    }

    // yn + pack + LDS (swizzled: chunk c -> c ^ ((c>>1)&7))
    const float inv = 1.0f / se;
    uint4 pka, pkb;
    unsigned short* p0v = (unsigned short*)&pka;
    unsigned short* p1v = (unsigned short*)&pkb;
#pragma unroll
    for (int j = 0; j < 16; ++j) {
      float e  = __expf(a[j] - M) * inv;
      float yn = (oBase + j == best) ? e : -e;
      sacc[j] += yn * a[j];
      unsigned short hv = f2bf(yn);
      if (j < 8) p0v[j] = hv; else p1v[j - 8] = hv;
    }
    const int c0 = 2 * lane, c1 = 2 * lane + 1;
    const int sp0 = c0 ^ ((c0 >> 1) & 7);
    const int sp1 = c1 ^ ((c1 >> 1) & 7);
    *(uint4*)&tile[r][sp0 * 8] = pka;
    *(uint4*)&tile[r][sp1 * 8] = pkb;
  }
  __syncthreads();

  // transposed writeout: thread covers o = t + 256*i; writes the full 64 B
  // batch-span (32 rows x bf16) of ynT row o -> whole-sector stores.
#pragma unroll
  for (int i = 0; i < 4; ++i) {
    const int o   = t + 256 * i;
    const int c   = o >> 3;
    const int sp  = c ^ ((c >> 1) & 7);
    const int off = o & 7;
    unsigned short buf[32];
#pragma unroll
    for (int r = 0; r < 32; ++r) buf[r] = tile[r][sp * 8 + off];
    unsigned short* dst = &ynT[(size_t)o * BATCH + b0];
    *(uint4*)&dst[0]  = *(const uint4*)&buf[0];
    *(uint4*)&dst[8]  = *(const uint4*)&buf[8];
    *(uint4*)&dst[16] = *(const uint4*)&buf[16];
    *(uint4*)&dst[24] = *(const uint4*)&buf[24];
  }
  __syncthreads();

  // in-block spart reduction: reuse tile LDS as float[4][1024]
  float* fred = (float*)tile;
#pragma unroll
  for (int j = 0; j < 16; j += 4)
    *(f32x4*)&fred[wave * 1024 + oBase + j] =
        *(const f32x4*)&sacc[j];
  __syncthreads();
  {
    const int o4 = t * 4;
    f32x4 s0 = *(const f32x4*)&fred[o4];
    f32x4 s1 = *(const f32x4*)&fred[1024 + o4];
    f32x4 s2 = *(const f32x4*)&fred[2048 + o4];
    f32x4 s3 = *(const f32x4*)&fred[3072 + o4];
    f32x4 sum = s0 + s1 + s2 + s3;
    *(f32x4*)&s_part[(size_t)blockIdx.x * OUTF + o4] = sum;
  }
}

// ---------------------------------------------------------------------------
// Kernel 5: block id -> o = (id&7)<<7 | id>>3  (XCD-local spart lines)
//   sb = (sum_{k<256} s_part[k][o]) / B
//   out[o][i] = rate[o] * (sum_z bf16 Cpart[z][o][i]/B - sb*W[o][i])
// ---------------------------------------------------------------------------
__global__ __launch_bounds__(256) void k_final(
    const unsigned short* __restrict__ Cp, const float* __restrict__ W,
    const float* __restrict__ s_part, const float* __restrict__ rate,
    float* __restrict__ out) {
  __shared__ float sred[256];
  const int t  = threadIdx.x;
  const int id = blockIdx.x;
  const int o  = ((id & 7) << 7) | (id >> 3);
  sred[t] = s_part[(size_t)t * OUTF + o];
  __syncthreads();
  for (int s2 = 128; s2 > 0; s2 >>= 1) {
    if (t < s2) sred[t] += sred[t + s2];
    __syncthreads();
  }
  const float sb = sred[0] * INV_B;
  const float rt = rate[o];
  const int i0 = t * 4;
  float cx = 0, cy = 0, cz = 0, cw = 0;
#pragma unroll
  for (int z = 0; z < SPLITZ; ++z) {
    ushort4 h = *(const ushort4*)&Cp[(size_t)z * (1024u * 1024u) +
                                     (size_t)o * INF_ + i0];
    cx += bf2f(h.x); cy += bf2f(h.y); cz += bf2f(h.z); cw += bf2f(h.w);
  }
  float4 w = *(const float4*)&W[(size_t)o * INF_ + i0];
  float4 r;
  r.x = rt * (cx * INV_B - sb * w.x);
  r.y = rt * (cy * INV_B - sb * w.y);
  r.z = rt * (cz * INV_B - sb * w.z);
  r.w = rt * (cw * INV_B - sb * w.w);
  *(float4*)&out[(size_t)o * INF_ + i0] = r;
}

// ---------------------------------------------------------------------------
// Workspace layout (bytes):
//   0        : ub bf16 [8192][1024] 16 MB (GEMM1 out; dead after k_softhebb)
//              REUSED (with xb) as GEMM2 bf16 Cpart[16][1024][1024] = 32 MB
//   16777216 : xb  bf16 16 MB (dead after GEMM1)
//   33554432 : xT  bf16 [1024][8192] 16 MB
//   50331648 : ynT bf16 [1024][8192] 16 MB
//   67108864 : Wb  bf16 2 MB
//   69206016 : rate fp32 [1024] 4 KB
//   69210112 : s_part fp32 [256][1024] 1 MB
//   total ~70.2 MB
// ---------------------------------------------------------------------------
extern "C" void kernel_launch(void* const* d_in, const int* in_sizes, int n_in,
                              void* d_out, int out_size, void* d_ws, size_t ws_size,
                              hipStream_t stream) {
  const float* x    = (const float*)d_in[0];
  const float* W    = (const float*)d_in[1];
  const float* bias = (const float*)d_in[2];
  float* out = (float*)d_out;
  char* ws = (char*)d_ws;

  unsigned short* ub    = (unsigned short*)(ws + 0);
  unsigned short* xb    = (unsigned short*)(ws + 16777216);
  unsigned short* xT    = (unsigned short*)(ws + 33554432);
  unsigned short* ynT   = (unsigned short*)(ws + 50331648);
  unsigned short* Wb    = (unsigned short*)(ws + 67108864);
  float*          rate  = (float*)(ws + 69206016);
  float*          spart = (float*)(ws + 69210112);

  k_convert<<<dim3(3072), 256, 0, stream>>>(x, xb, xT, W, Wb, rate);
  // GEMM1: u[b][o] = x@W.T + b (bf16 out), M=8192 N=1024 K=1024, XCD-grouped
  k_gemm<<<dim3(512), 256, 0, stream>>>(xb, Wb, 1024, 1024, 1024,
                                        ub, 1024, bias, 0);
  // fused softmax-stats + exact-argmax repair + yn / ynT / spart
  k_softhebb<<<dim3(256), 256, 0, stream>>>(ub, x, W, ynT, spart);
  // GEMM2: C[o][i] = yn.T@x, M=1024 N=1024 K=8192, split-K x16 (bf16
  // partials overwrite ub+xb, both dead)
  k_gemm<<<dim3(1024), 256, 0, stream>>>(ynT, xT, 8192, 8192, 512,
                                         ws, 1024, nullptr, 1);
  k_final<<<dim3(1024), 256, 0, stream>>>((const unsigned short*)ws, W, spart,
                                          rate, out);
}

// Round 7
// 155.337 us; speedup vs baseline: 1.0561x; 1.0561x over previous
//
#include <hip/hip_runtime.h>

// Problem constants
#define BATCH 8192
#define INF_  1024   // IN
#define OUTF  1024   // OUT
#define INV_B (1.0f/8192.0f)
#define RATE_C 1e-3f
#define SPLITZ 16    // GEMM2 split-K factor (bf16 partials)

typedef __bf16 bf16x8 __attribute__((ext_vector_type(8)));
typedef float  f32x4  __attribute__((ext_vector_type(4)));
typedef const __attribute__((address_space(1))) unsigned int* gas_t;
typedef __attribute__((address_space(3))) unsigned int* las_t;

// fp32 -> bf16 round-to-nearest-even
static __device__ __forceinline__ unsigned short f2bf(float f) {
  unsigned int u = __float_as_uint(f);
  u += 0x7fffu + ((u >> 16) & 1u);
  return (unsigned short)(u >> 16);
}
static __device__ __forceinline__ float bf2f(unsigned short h) {
  return __uint_as_float(((unsigned int)h) << 16);
}

// ---------------------------------------------------------------------------
// Kernel 1 (merged): blocks [0,2048): x -> xb (bf16) + xT (bf16, transposed)
//                    blocks [2048,3072): W row -> Wb + rate[o]
// ---------------------------------------------------------------------------
__global__ __launch_bounds__(256) void k_convert(
    const float* __restrict__ x, unsigned short* __restrict__ xb,
    unsigned short* __restrict__ xT, const float* __restrict__ W,
    unsigned short* __restrict__ Wb, float* __restrict__ rate) {
  const int t = threadIdx.x;
  if (blockIdx.x >= 2048) {
    __shared__ float red[256];
    const int o = blockIdx.x - 2048;
    float4 v = *(const float4*)&W[(size_t)o * INF_ + t * 4];
    ushort4 h;
    h.x = f2bf(v.x); h.y = f2bf(v.y); h.z = f2bf(v.z); h.w = f2bf(v.w);
    *(ushort4*)&Wb[(size_t)o * INF_ + t * 4] = h;
    red[t] = v.x * v.x + v.y * v.y + v.z * v.z + v.w * v.w;
    __syncthreads();
    for (int s = 128; s > 0; s >>= 1) {
      if (t < s) red[t] += red[t + s];
      __syncthreads();
    }
    if (t == 0) {
      float nrm = sqrtf(red[0]);
      rate[o] = RATE_C * sqrtf(fabsf(1.0f - nrm));
    }
    return;
  }
  // ---- x convert + transpose (64x64 tile), packed-u32 LDS ----
  __shared__ unsigned int t32[64][33];
  const int bx = blockIdx.x & 15;
  const int by = blockIdx.x >> 4;
  const int r0 = by * 64;
  const int c0 = bx * 64;
  const int m = t & 15;
  const int q = t >> 4;
#pragma unroll
  for (int p = 0; p < 2; ++p) {
    const int r2 = p * 16 + q;
    const int b  = r0 + 2 * r2;
    float4 v0 = *(const float4*)&x[(size_t)b * INF_ + c0 + 4 * m];
    float4 v1 = *(const float4*)&x[(size_t)(b + 1) * INF_ + c0 + 4 * m];
    ushort4 h0, h1;
    h0.x = f2bf(v0.x); h0.y = f2bf(v0.y); h0.z = f2bf(v0.z); h0.w = f2bf(v0.w);
    h1.x = f2bf(v1.x); h1.y = f2bf(v1.y); h1.z = f2bf(v1.z); h1.w = f2bf(v1.w);
    *(ushort4*)&xb[(size_t)b * INF_ + c0 + 4 * m] = h0;
    *(ushort4*)&xb[(size_t)(b + 1) * INF_ + c0 + 4 * m] = h1;
    t32[4 * m + 0][r2] = (unsigned int)h0.x | ((unsigned int)h1.x << 16);
    t32[4 * m + 1][r2] = (unsigned int)h0.y | ((unsigned int)h1.y << 16);
    t32[4 * m + 2][r2] = (unsigned int)h0.z | ((unsigned int)h1.z << 16);
    t32[4 * m + 3][r2] = (unsigned int)h0.w | ((unsigned int)h1.w << 16);
  }
  __syncthreads();
  const int c  = t >> 2;
  const int sg = t & 3;
  unsigned int vb[8];
#pragma unroll
  for (int k = 0; k < 8; ++k) vb[k] = t32[c][sg * 8 + k];
  unsigned short* dst = &xT[(size_t)(c0 + c) * BATCH + r0 + sg * 16];
  *(uint4*)&dst[0] = make_uint4(vb[0], vb[1], vb[2], vb[3]);
  *(uint4*)&dst[8] = make_uint4(vb[4], vb[5], vb[6], vb[7]);
}

// ---------------------------------------------------------------------------
// Kernel 2/5: NT bf16 GEMM, 128x128 tile, BK=64, global_load_lds width=16
// staging + XOR chunk swizzle. XCD-aware 1-D grids.
//   mode 0 (GEMM1, 512 blocks): bf16 C (= u) with bias.
//   mode 1 (GEMM2, 1024 blocks): bf16 partial K-slices.
// Epilogue is STAGED through LDS (pitch 132 halves: b16 fragment writes are
// conflict-free — quad-groups land on banks +8 apart; readback/stores are
// full-sector 256 B-per-row coalesced) instead of scattered b16 stores.
// ---------------------------------------------------------------------------
__global__ __launch_bounds__(256, 3) void k_gemm(
    const unsigned short* __restrict__ A, const unsigned short* __restrict__ B,
    int lda, int ldb, int kChunk, void* __restrict__ C, int ldc,
    const float* __restrict__ bias, int mode) {
  __shared__ unsigned short smem[128 * 132];  // staging (32 KB) / epilogue (33 KB)
  unsigned short* As = smem;
  unsigned short* Bs = smem + 128 * 64;
  const int t  = threadIdx.x;
  const int id = blockIdx.x;
  int bx, by, bz;
  if (mode == 0) {
    by = (id & 7) | ((id >> 6) << 3);
    bx = (id >> 3) & 7;
    bz = 0;
  } else {
    bz = ((id & 7) << 1) | ((id >> 3) & 1);
    by = (id >> 4) & 7;
    bx = id >> 7;
  }
  const int m0   = by * 128;
  const int n0   = bx * 128;
  const int k0   = bz * kChunk;
  const int lane = t & 63;
  const int wave = t >> 6;
  const int sr   = lane >> 3;
  const int scx  = ((lane & 7) ^ sr) * 8;
  const int wm   = (wave >> 1) * 64;
  const int wn   = (wave & 1) * 64;
  const int fm   = lane & 15;
  const int fk   = (lane >> 4) * 8;

  f32x4 acc[4][4] = {};

  const int ldsRow0 = wave * 8;
  const size_t gArow = (size_t)(m0 + ldsRow0 + sr) * lda + scx;
  const size_t gBrow = (size_t)(n0 + ldsRow0 + sr) * ldb + scx;

  for (int ks = 0; ks < kChunk; ks += 64) {
    const int k = k0 + ks;
#pragma unroll
    for (int j = 0; j < 4; ++j) {
      __builtin_amdgcn_global_load_lds(
          (gas_t)&A[gArow + (size_t)j * 32 * lda + k],
          (las_t)&As[(ldsRow0 + j * 32) * 64], 16, 0, 0);
      __builtin_amdgcn_global_load_lds(
          (gas_t)&B[gBrow + (size_t)j * 32 * ldb + k],
          (las_t)&Bs[(ldsRow0 + j * 32) * 64], 16, 0, 0);
    }
    __syncthreads();
#pragma unroll
    for (int kk = 0; kk < 64; kk += 32) {
      bf16x8 af[4], bf[4];
      const int swz = ((((kk + fk) >> 3) ^ (fm & 7)) << 3);
#pragma unroll
      for (int i = 0; i < 4; ++i)
        af[i] = *(const bf16x8*)&As[(wm + i * 16 + fm) * 64 + swz];
#pragma unroll
      for (int i = 0; i < 4; ++i)
        bf[i] = *(const bf16x8*)&Bs[(wn + i * 16 + fm) * 64 + swz];
#pragma unroll
      for (int mt = 0; mt < 4; ++mt)
#pragma unroll
        for (int nt = 0; nt < 4; ++nt)
          acc[mt][nt] = __builtin_amdgcn_mfma_f32_16x16x32_bf16(
              af[mt], bf[nt], acc[mt][nt], 0, 0, 0);
    }
    __syncthreads();
  }

  // Staged epilogue. C/D layout (m89): col = lane&15, row = (lane>>4)*4 + reg
  const int er = (lane >> 4) * 4;
#pragma unroll
  for (int nt = 0; nt < 4; ++nt) {
    const int cc = wn + nt * 16 + fm;
    const float bv = (mode == 0) ? bias[n0 + cc] : 0.0f;
#pragma unroll
    for (int mt = 0; mt < 4; ++mt) {
      const int rr = wm + mt * 16 + er;
#pragma unroll
      for (int r = 0; r < 4; ++r)
        smem[(rr + r) * 132 + cc] = f2bf(acc[mt][nt][r] + bv);
    }
  }
  __syncthreads();
  unsigned short* Cb = (mode == 0)
      ? (unsigned short*)C
      : (unsigned short*)C + (size_t)bz * (1024u * 1024u);
#pragma unroll
  for (int i = 0; i < 8; ++i) {
    const int row = i * 16 + (t >> 4);
    const int ch  = (t & 15) * 8;
    const unsigned short* src = &smem[row * 132 + ch];
    unsigned short* dst = &Cb[(size_t)(m0 + row) * ldc + n0 + ch];
    *(uint2*)&dst[0] = *(const uint2*)&src[0];
    *(uint2*)&dst[4] = *(const uint2*)&src[4];
  }
}

// ---------------------------------------------------------------------------
// Kernel 3: per-row stats, wave-per-row (4 rows/block, 2048 blocks = 8/CU,
// latency fully hidden). bf16 u input. Reductions via __shfl_xor
// butterflies. Exact argmax: candidates within 0.10 of approx max get
// logits recomputed in fp32 from x,W (covers bf16-storage err <=0.03 +
// GEMM err <=0.015). First-index-wins tie rule matches jnp.argmax.
// ---------------------------------------------------------------------------
__global__ __launch_bounds__(256) void k_row_stats(
    const unsigned short* __restrict__ ub, const float* __restrict__ x,
    const float* __restrict__ W, float* __restrict__ rowmax,
    float* __restrict__ rowinv, int* __restrict__ rowarg) {
  __shared__ int cands[4][32];
  __shared__ int cnt[4];
  const int lane = threadIdx.x & 63;
  const int wave = threadIdx.x >> 6;
  const int b    = blockIdx.x * 4 + wave;
  const int oBase = lane * 16;

  // load u row (bf16 -> fp32): 32 B/lane, 2 KB contiguous per wave
  float a[16];
  {
    uint4 q0 = *(const uint4*)&ub[(size_t)b * OUTF + oBase];
    uint4 q1 = *(const uint4*)&ub[(size_t)b * OUTF + oBase + 8];
    const unsigned int* qa = (const unsigned int*)&q0;
    const unsigned int* qb = (const unsigned int*)&q1;
#pragma unroll
    for (int c = 0; c < 4; ++c) {
      a[2 * c]         = __uint_as_float(qa[c] << 16);
      a[2 * c + 1]     = __uint_as_float(qa[c] & 0xffff0000u);
      a[8 + 2 * c]     = __uint_as_float(qb[c] << 16);
      a[8 + 2 * c + 1] = __uint_as_float(qb[c] & 0xffff0000u);
    }
  }
  float mv = a[0]; int mi = oBase;
#pragma unroll
  for (int j = 1; j < 16; ++j)
    if (a[j] > mv) { mv = a[j]; mi = oBase + j; }
#pragma unroll
  for (int off = 1; off < 64; off <<= 1) {
    float ov = __shfl_xor(mv, off);
    int   oi = __shfl_xor(mi, off);
    if (ov > mv || (ov == mv && oi < mi)) { mv = ov; mi = oi; }
  }
  const float M = mv;
  float se = 0.0f;
#pragma unroll
  for (int j = 0; j < 16; ++j) se += __expf(a[j] - M);
#pragma unroll
  for (int off = 1; off < 64; off <<= 1) se += __shfl_xor(se, off);

  const float thr = M - 0.10f;
  unsigned int cflags = 0;
  int ccount = 0;
#pragma unroll
  for (int j = 0; j < 16; ++j)
    if (a[j] >= thr) { cflags |= (1u << j); ++ccount; }
  int tot = ccount;
#pragma unroll
  for (int off = 1; off < 64; off <<= 1) tot += __shfl_xor(tot, off);

  int best = mi;
  if (tot > 1) {
    if (lane == 0) cnt[wave] = 0;
    for (int j = 0; j < 16; ++j)
      if (cflags & (1u << j)) {
        int p = atomicAdd(&cnt[wave], 1);
        if (p < 32) cands[wave][p] = oBase + j;
      }
    int nc = cnt[wave]; if (nc > 32) nc = 32;
    float xr[16];
    const float* xp = &x[(size_t)b * INF_ + oBase];
#pragma unroll
    for (int j = 0; j < 16; j += 4) {
      float4 v = *(const float4*)&xp[j];
      xr[j] = v.x; xr[j + 1] = v.y; xr[j + 2] = v.z; xr[j + 3] = v.w;
    }
    float bv = -3.4e38f; int bi = 0x7fffffff;
    for (int c = 0; c < nc; ++c) {
      const int o = cands[wave][c];
      const float* wp = &W[(size_t)o * INF_ + oBase];
      float d = 0.0f;
#pragma unroll
      for (int j = 0; j < 16; j += 4) {
        float4 v = *(const float4*)&wp[j];
        d += xr[j] * v.x + xr[j + 1] * v.y + xr[j + 2] * v.z +
             xr[j + 3] * v.w;
      }
#pragma unroll
      for (int off = 1; off < 64; off <<= 1) d += __shfl_xor(d, off);
      if (d > bv || (d == bv && o < bi)) { bv = d; bi = o; }
    }
    best = bi;
  }
  if (lane == 0) {
    rowmax[b] = M;
    rowinv[b] = 1.0f / se;
    rowarg[b] = best;
  }
}

// ---------------------------------------------------------------------------
// Kernel 4: yn = negate_non_maximal(softmax(u)) from bf16 u; write ynT
// (bf16 [OUT][B], transposed via LDS) and per-block spart[by][o] = sum yn*u.
// Grid (4,128): o0 = bx*256, b0 = by*64. 512 blocks = 2/CU.
// ---------------------------------------------------------------------------
__global__ __launch_bounds__(256) void k_yn(
    const unsigned short* __restrict__ ub, const float* __restrict__ rowmax,
    const float* __restrict__ rowinv, const int* __restrict__ rowarg,
    unsigned short* __restrict__ ynT, float* __restrict__ s_part) {
  __shared__ unsigned short tile[256][72];
  __shared__ float smax[64], sinv[64];
  __shared__ int   sarg[64];
  const int t  = threadIdx.x;
  const int o0 = blockIdx.x * 256;
  const int b0 = blockIdx.y * 64;
  if (t < 64) {
    smax[t] = rowmax[b0 + t];
    sinv[t] = rowinv[b0 + t];
    sarg[t] = rowarg[b0 + t];
  }
  __syncthreads();
  const int o = o0 + t;
  float sacc = 0.0f;
#pragma unroll
  for (int g = 0; g < 8; ++g) {
    uint4 pkv;
    unsigned short* pk = (unsigned short*)&pkv;
#pragma unroll
    for (int j = 0; j < 8; ++j) {
      const int r = g * 8 + j;
      float uu  = bf2f(ub[(size_t)(b0 + r) * OUTF + o]);
      float ysm = __expf(uu - smax[r]) * sinv[r];
      float yn  = (o == sarg[r]) ? ysm : -ysm;
      sacc += yn * uu;
      pk[j] = f2bf(yn);
    }
    *(uint4*)&tile[t][g * 8] = pkv;
  }
  s_part[(size_t)blockIdx.y * OUTF + o] = sacc;
  __syncthreads();
  // write ynT[o0+row][b0 .. b0+63], 128 B contiguous per 8-lane group
#pragma unroll
  for (int it = 0; it < 8; ++it) {
    const int row = it * 32 + (t >> 3);
    const int seg = (t & 7) * 8;  // halves
    uint4 vv = *(const uint4*)&tile[row][seg];
    *(uint4*)&ynT[(size_t)(o0 + row) * BATCH + b0 + seg] = vv;
  }
}

// ---------------------------------------------------------------------------
// Kernel 6: block id -> o = (id&7)<<7 | id>>3  (XCD-local spart lines)
//   sb = (sum_{k<128} s_part[k][o]) / B
//   out[o][i] = rate[o] * (sum_z bf16 Cpart[z][o][i]/B - sb*W[o][i])
// ---------------------------------------------------------------------------
__global__ __launch_bounds__(256) void k_final(
    const unsigned short* __restrict__ Cp, const float* __restrict__ W,
    const float* __restrict__ s_part, const float* __restrict__ rate,
    float* __restrict__ out) {
  __shared__ float sred[128];
  const int t  = threadIdx.x;
  const int id = blockIdx.x;
  const int o  = ((id & 7) << 7) | (id >> 3);
  if (t < 128) sred[t] = s_part[(size_t)t * OUTF + o];
  __syncthreads();
  for (int s2 = 64; s2 > 0; s2 >>= 1) {
    if (t < s2) sred[t] += sred[t + s2];
    __syncthreads();
  }
  const float sb = sred[0] * INV_B;
  const float rt = rate[o];
  const int i0 = t * 4;
  float cx = 0, cy = 0, cz = 0, cw = 0;
#pragma unroll
  for (int z = 0; z < SPLITZ; ++z) {
    ushort4 h = *(const ushort4*)&Cp[(size_t)z * (1024u * 1024u) +
                                     (size_t)o * INF_ + i0];
    cx += bf2f(h.x); cy += bf2f(h.y); cz += bf2f(h.z); cw += bf2f(h.w);
  }
  float4 w = *(const float4*)&W[(size_t)o * INF_ + i0];
  float4 r;
  r.x = rt * (cx * INV_B - sb * w.x);
  r.y = rt * (cy * INV_B - sb * w.y);
  r.z = rt * (cz * INV_B - sb * w.z);
  r.w = rt * (cw * INV_B - sb * w.w);
  *(float4*)&out[(size_t)o * INF_ + i0] = r;
}

// ---------------------------------------------------------------------------
// Workspace layout (bytes):
//   0        : ub bf16 [8192][1024] 16 MB (GEMM1 out; dead after k_yn)
//              REUSED (with xb) as GEMM2 bf16 Cpart[16][1024][1024] = 32 MB
//   16777216 : xb  bf16 16 MB (dead after GEMM1)
//   33554432 : xT  bf16 [1024][8192] 16 MB
//   50331648 : ynT bf16 [1024][8192] 16 MB
//   67108864 : Wb  bf16 2 MB
//   69206016 : rate fp32 [1024] 4 KB
//   69210112 : s_part fp32 [128][1024] 512 KB
//   69734400 : rowmax fp32 [8192] 32 KB
//   69767168 : rowinv fp32 [8192] 32 KB
//   69799936 : rowarg int  [8192] 32 KB
//   total ~69.9 MB
// ---------------------------------------------------------------------------
extern "C" void kernel_launch(void* const* d_in, const int* in_sizes, int n_in,
                              void* d_out, int out_size, void* d_ws, size_t ws_size,
                              hipStream_t stream) {
  const float* x    = (const float*)d_in[0];
  const float* W    = (const float*)d_in[1];
  const float* bias = (const float*)d_in[2];
  float* out = (float*)d_out;
  char* ws = (char*)d_ws;

  unsigned short* ub    = (unsigned short*)(ws + 0);
  unsigned short* xb    = (unsigned short*)(ws + 16777216);
  unsigned short* xT    = (unsigned short*)(ws + 33554432);
  unsigned short* ynT   = (unsigned short*)(ws + 50331648);
  unsigned short* Wb    = (unsigned short*)(ws + 67108864);
  float*          rate  = (float*)(ws + 69206016);
  float*          spart = (float*)(ws + 69210112);
  float*          rmax  = (float*)(ws + 69734400);
  float*          rinv  = (float*)(ws + 69767168);
  int*            rarg  = (int*)  (ws + 69799936);

  k_convert<<<dim3(3072), 256, 0, stream>>>(x, xb, xT, W, Wb, rate);
  // GEMM1: u[b][o] = x@W.T + b (bf16 out), M=8192 N=1024 K=1024, XCD-grouped
  k_gemm<<<dim3(512), 256, 0, stream>>>(xb, Wb, 1024, 1024, 1024,
                                        ub, 1024, bias, 0);
  // high-occupancy stats (2048 blocks) + exact-argmax repair
  k_row_stats<<<dim3(2048), 256, 0, stream>>>(ub, x, W, rmax, rinv, rarg);
  // streaming yn / ynT / spart
  k_yn<<<dim3(4, 128), 256, 0, stream>>>(ub, rmax, rinv, rarg, ynT, spart);
  // GEMM2: C[o][i] = yn.T@x, M=1024 N=1024 K=8192, split-K x16 (bf16
  // partials overwrite ub+xb, both dead)
  k_gemm<<<dim3(1024), 256, 0, stream>>>(ynT, xT, 8192, 8192, 512,
                                         ws, 1024, nullptr, 1);
  k_final<<<dim3(1024), 256, 0, stream>>>((const unsigned short*)ws, W, spart,
                                          rate, out);
}

// Round 8
// 153.589 us; speedup vs baseline: 1.0681x; 1.0114x over previous
//
#include <hip/hip_runtime.h>

// Problem constants
#define BATCH 8192
#define INF_  1024   // IN
#define OUTF  1024   // OUT
#define INV_B (1.0f/8192.0f)
#define RATE_C 1e-3f
#define SPLITZ 8     // GEMM2 split-K factor (bf16 partials)

typedef __bf16 bf16x8 __attribute__((ext_vector_type(8)));
typedef float  f32x4  __attribute__((ext_vector_type(4)));
typedef float  f32x16 __attribute__((ext_vector_type(16)));
typedef const __attribute__((address_space(1))) unsigned int* gas_t;
typedef __attribute__((address_space(3))) unsigned int* las_t;

// fp32 -> bf16 round-to-nearest-even
static __device__ __forceinline__ unsigned short f2bf(float f) {
  unsigned int u = __float_as_uint(f);
  u += 0x7fffu + ((u >> 16) & 1u);
  return (unsigned short)(u >> 16);
}
static __device__ __forceinline__ float bf2f(unsigned short h) {
  return __uint_as_float(((unsigned int)h) << 16);
}

// ---------------------------------------------------------------------------
// Kernel 1 (merged): blocks [0,2048): x -> xb (bf16) + xT (bf16, transposed)
//                    blocks [2048,3072): W row -> Wb + rate[o]
// ---------------------------------------------------------------------------
__global__ __launch_bounds__(256) void k_convert(
    const float* __restrict__ x, unsigned short* __restrict__ xb,
    unsigned short* __restrict__ xT, const float* __restrict__ W,
    unsigned short* __restrict__ Wb, float* __restrict__ rate) {
  const int t = threadIdx.x;
  if (blockIdx.x >= 2048) {
    __shared__ float red[256];
    const int o = blockIdx.x - 2048;
    float4 v = *(const float4*)&W[(size_t)o * INF_ + t * 4];
    ushort4 h;
    h.x = f2bf(v.x); h.y = f2bf(v.y); h.z = f2bf(v.z); h.w = f2bf(v.w);
    *(ushort4*)&Wb[(size_t)o * INF_ + t * 4] = h;
    red[t] = v.x * v.x + v.y * v.y + v.z * v.z + v.w * v.w;
    __syncthreads();
    for (int s = 128; s > 0; s >>= 1) {
      if (t < s) red[t] += red[t + s];
      __syncthreads();
    }
    if (t == 0) {
      float nrm = sqrtf(red[0]);
      rate[o] = RATE_C * sqrtf(fabsf(1.0f - nrm));
    }
    return;
  }
  // ---- x convert + transpose (64x64 tile), packed-u32 LDS ----
  __shared__ unsigned int t32[64][33];
  const int bx = blockIdx.x & 15;
  const int by = blockIdx.x >> 4;
  const int r0 = by * 64;
  const int c0 = bx * 64;
  const int m = t & 15;
  const int q = t >> 4;
#pragma unroll
  for (int p = 0; p < 2; ++p) {
    const int r2 = p * 16 + q;
    const int b  = r0 + 2 * r2;
    float4 v0 = *(const float4*)&x[(size_t)b * INF_ + c0 + 4 * m];
    float4 v1 = *(const float4*)&x[(size_t)(b + 1) * INF_ + c0 + 4 * m];
    ushort4 h0, h1;
    h0.x = f2bf(v0.x); h0.y = f2bf(v0.y); h0.z = f2bf(v0.z); h0.w = f2bf(v0.w);
    h1.x = f2bf(v1.x); h1.y = f2bf(v1.y); h1.z = f2bf(v1.z); h1.w = f2bf(v1.w);
    *(ushort4*)&xb[(size_t)b * INF_ + c0 + 4 * m] = h0;
    *(ushort4*)&xb[(size_t)(b + 1) * INF_ + c0 + 4 * m] = h1;
    t32[4 * m + 0][r2] = (unsigned int)h0.x | ((unsigned int)h1.x << 16);
    t32[4 * m + 1][r2] = (unsigned int)h0.y | ((unsigned int)h1.y << 16);
    t32[4 * m + 2][r2] = (unsigned int)h0.z | ((unsigned int)h1.z << 16);
    t32[4 * m + 3][r2] = (unsigned int)h0.w | ((unsigned int)h1.w << 16);
  }
  __syncthreads();
  const int c  = t >> 2;
  const int sg = t & 3;
  unsigned int vb[8];
#pragma unroll
  for (int k = 0; k < 8; ++k) vb[k] = t32[c][sg * 8 + k];
  unsigned short* dst = &xT[(size_t)(c0 + c) * BATCH + r0 + sg * 16];
  *(uint4*)&dst[0] = make_uint4(vb[0], vb[1], vb[2], vb[3]);
  *(uint4*)&dst[8] = make_uint4(vb[4], vb[5], vb[6], vb[7]);
}

// ---------------------------------------------------------------------------
// Kernel 2/5: NT bf16 GEMM, 128x128 tile, BK=64, global_load_lds width=16
// staging + XOR chunk swizzle. MFMA: 32x32x16 (wave tile 64x64 = 2x2 of
// 32x32) — 16 MFMAs/iter instead of 32 at the same ds_read count, ~20%
// higher FLOP/cyc on the matrix pipe (m119: 2495 vs 2075 TF).
//   A-frag: A[m=lane&31][k=(lane>>5)*8+j]; C/D (m74/m101):
//   col=lane&31, row=(r&3)+8*(r>>2)+4*(lane>>5).
// XCD-aware 1-D grids:
//   mode 0 (GEMM1, 512 blocks): by%8==id%8 -> XCD-local A strips + full Wb.
//   mode 1 (GEMM2, 512 blocks): bz=id&7 -> XCD owns one K=1024 slice.
// Staged LDS epilogue (pitch 132) -> full-sector coalesced bf16 stores.
// ---------------------------------------------------------------------------
__global__ __launch_bounds__(256, 3) void k_gemm(
    const unsigned short* __restrict__ A, const unsigned short* __restrict__ B,
    int lda, int ldb, int kChunk, void* __restrict__ C, int ldc,
    const float* __restrict__ bias, int mode) {
  __shared__ unsigned short smem[128 * 132];  // staging (32 KB) / epilogue (33 KB)
  unsigned short* As = smem;
  unsigned short* Bs = smem + 128 * 64;
  const int t  = threadIdx.x;
  const int id = blockIdx.x;
  int bx, by, bz;
  if (mode == 0) {
    by = (id & 7) | ((id >> 6) << 3);
    bx = (id >> 3) & 7;
    bz = 0;
  } else {
    bz = id & 7;
    by = (id >> 3) & 7;
    bx = (id >> 6) & 7;
  }
  const int m0   = by * 128;
  const int n0   = bx * 128;
  const int k0   = bz * kChunk;
  const int lane = t & 63;
  const int wave = t >> 6;
  const int sr   = lane >> 3;
  const int scx  = ((lane & 7) ^ sr) * 8;
  const int wm   = (wave >> 1) * 64;
  const int wn   = (wave & 1) * 64;
  const int fm   = lane & 31;           // row within 32-tile
  const int fh   = lane >> 5;           // half-wave: k-offset selector

  f32x16 acc[2][2] = {};

  const int ldsRow0 = wave * 8;
  const size_t gArow = (size_t)(m0 + ldsRow0 + sr) * lda + scx;
  const size_t gBrow = (size_t)(n0 + ldsRow0 + sr) * ldb + scx;

  for (int ks = 0; ks < kChunk; ks += 64) {
    const int k = k0 + ks;
#pragma unroll
    for (int j = 0; j < 4; ++j) {
      __builtin_amdgcn_global_load_lds(
          (gas_t)&A[gArow + (size_t)j * 32 * lda + k],
          (las_t)&As[(ldsRow0 + j * 32) * 64], 16, 0, 0);
      __builtin_amdgcn_global_load_lds(
          (gas_t)&B[gBrow + (size_t)j * 32 * ldb + k],
          (las_t)&Bs[(ldsRow0 + j * 32) * 64], 16, 0, 0);
    }
    __syncthreads();
#pragma unroll
    for (int kk = 0; kk < 64; kk += 16) {
      // chunk index of this lane's 8-half k-slice, then XOR row swizzle
      const int ckk = (kk >> 3) + fh;          // 16-B chunk 0..7
      const int swz = (ckk ^ (lane & 7)) << 3; // halves
      bf16x8 af[2], bf[2];
#pragma unroll
      for (int i = 0; i < 2; ++i)
        af[i] = *(const bf16x8*)&As[(wm + i * 32 + fm) * 64 + swz];
#pragma unroll
      for (int i = 0; i < 2; ++i)
        bf[i] = *(const bf16x8*)&Bs[(wn + i * 32 + fm) * 64 + swz];
#pragma unroll
      for (int mt = 0; mt < 2; ++mt)
#pragma unroll
        for (int nt = 0; nt < 2; ++nt)
          acc[mt][nt] = __builtin_amdgcn_mfma_f32_32x32x16_bf16(
              af[mt], bf[nt], acc[mt][nt], 0, 0, 0);
    }
    __syncthreads();
  }

  // Staged epilogue. C/D: col = lane&31, row = (r&3)+8*(r>>2)+4*(lane>>5)
#pragma unroll
  for (int nt = 0; nt < 2; ++nt) {
    const int cc = wn + nt * 32 + fm;
    const float bv = (mode == 0) ? bias[n0 + cc] : 0.0f;
#pragma unroll
    for (int mt = 0; mt < 2; ++mt) {
#pragma unroll
      for (int r = 0; r < 16; ++r) {
        const int rr = wm + mt * 32 + (r & 3) + 8 * (r >> 2) + 4 * fh;
        smem[rr * 132 + cc] = f2bf(acc[mt][nt][r] + bv);
      }
    }
  }
  __syncthreads();
  unsigned short* Cb = (mode == 0)
      ? (unsigned short*)C
      : (unsigned short*)C + (size_t)bz * (1024u * 1024u);
#pragma unroll
  for (int i = 0; i < 8; ++i) {
    const int row = i * 16 + (t >> 4);
    const int ch  = (t & 15) * 8;
    const unsigned short* src = &smem[row * 132 + ch];
    unsigned short* dst = &Cb[(size_t)(m0 + row) * ldc + n0 + ch];
    *(uint2*)&dst[0] = *(const uint2*)&src[0];
    *(uint2*)&dst[4] = *(const uint2*)&src[4];
  }
}

// ---------------------------------------------------------------------------
// Kernel 3: per-row stats, wave-per-row (4 rows/block, 2048 blocks = 8/CU).
// bf16 u input; butterfly reductions; exact fp32 argmax repair (window 0.10).
// ---------------------------------------------------------------------------
__global__ __launch_bounds__(256) void k_row_stats(
    const unsigned short* __restrict__ ub, const float* __restrict__ x,
    const float* __restrict__ W, float* __restrict__ rowmax,
    float* __restrict__ rowinv, int* __restrict__ rowarg) {
  __shared__ int cands[4][32];
  __shared__ int cnt[4];
  const int lane = threadIdx.x & 63;
  const int wave = threadIdx.x >> 6;
  const int b    = blockIdx.x * 4 + wave;
  const int oBase = lane * 16;

  float a[16];
  {
    uint4 q0 = *(const uint4*)&ub[(size_t)b * OUTF + oBase];
    uint4 q1 = *(const uint4*)&ub[(size_t)b * OUTF + oBase + 8];
    const unsigned int* qa = (const unsigned int*)&q0;
    const unsigned int* qb = (const unsigned int*)&q1;
#pragma unroll
    for (int c = 0; c < 4; ++c) {
      a[2 * c]         = __uint_as_float(qa[c] << 16);
      a[2 * c + 1]     = __uint_as_float(qa[c] & 0xffff0000u);
      a[8 + 2 * c]     = __uint_as_float(qb[c] << 16);
      a[8 + 2 * c + 1] = __uint_as_float(qb[c] & 0xffff0000u);
    }
  }
  float mv = a[0]; int mi = oBase;
#pragma unroll
  for (int j = 1; j < 16; ++j)
    if (a[j] > mv) { mv = a[j]; mi = oBase + j; }
#pragma unroll
  for (int off = 1; off < 64; off <<= 1) {
    float ov = __shfl_xor(mv, off);
    int   oi = __shfl_xor(mi, off);
    if (ov > mv || (ov == mv && oi < mi)) { mv = ov; mi = oi; }
  }
  const float M = mv;
  float se = 0.0f;
#pragma unroll
  for (int j = 0; j < 16; ++j) se += __expf(a[j] - M);
#pragma unroll
  for (int off = 1; off < 64; off <<= 1) se += __shfl_xor(se, off);

  const float thr = M - 0.10f;
  unsigned int cflags = 0;
  int ccount = 0;
#pragma unroll
  for (int j = 0; j < 16; ++j)
    if (a[j] >= thr) { cflags |= (1u << j); ++ccount; }
  int tot = ccount;
#pragma unroll
  for (int off = 1; off < 64; off <<= 1) tot += __shfl_xor(tot, off);

  int best = mi;
  if (tot > 1) {
    if (lane == 0) cnt[wave] = 0;
    for (int j = 0; j < 16; ++j)
      if (cflags & (1u << j)) {
        int p = atomicAdd(&cnt[wave], 1);
        if (p < 32) cands[wave][p] = oBase + j;
      }
    int nc = cnt[wave]; if (nc > 32) nc = 32;
    float xr[16];
    const float* xp = &x[(size_t)b * INF_ + oBase];
#pragma unroll
    for (int j = 0; j < 16; j += 4) {
      float4 v = *(const float4*)&xp[j];
      xr[j] = v.x; xr[j + 1] = v.y; xr[j + 2] = v.z; xr[j + 3] = v.w;
    }
    float bv = -3.4e38f; int bi = 0x7fffffff;
    for (int c = 0; c < nc; ++c) {
      const int o = cands[wave][c];
      const float* wp = &W[(size_t)o * INF_ + oBase];
      float d = 0.0f;
#pragma unroll
      for (int j = 0; j < 16; j += 4) {
        float4 v = *(const float4*)&wp[j];
        d += xr[j] * v.x + xr[j + 1] * v.y + xr[j + 2] * v.z +
             xr[j + 3] * v.w;
      }
#pragma unroll
      for (int off = 1; off < 64; off <<= 1) d += __shfl_xor(d, off);
      if (d > bv || (d == bv && o < bi)) { bv = d; bi = o; }
    }
    best = bi;
  }
  if (lane == 0) {
    rowmax[b] = M;
    rowinv[b] = 1.0f / se;
    rowarg[b] = best;
  }
}

// ---------------------------------------------------------------------------
// Kernel 4: yn = negate_non_maximal(softmax(u)) from bf16 u; write ynT
// (bf16 [OUT][B], transposed via LDS) and per-block spart[by][o] = sum yn*u.
// ---------------------------------------------------------------------------
__global__ __launch_bounds__(256) void k_yn(
    const unsigned short* __restrict__ ub, const float* __restrict__ rowmax,
    const float* __restrict__ rowinv, const int* __restrict__ rowarg,
    unsigned short* __restrict__ ynT, float* __restrict__ s_part) {
  __shared__ unsigned short tile[256][72];
  __shared__ float smax[64], sinv[64];
  __shared__ int   sarg[64];
  const int t  = threadIdx.x;
  const int o0 = blockIdx.x * 256;
  const int b0 = blockIdx.y * 64;
  if (t < 64) {
    smax[t] = rowmax[b0 + t];
    sinv[t] = rowinv[b0 + t];
    sarg[t] = rowarg[b0 + t];
  }
  __syncthreads();
  const int o = o0 + t;
  float sacc = 0.0f;
#pragma unroll
  for (int g = 0; g < 8; ++g) {
    uint4 pkv;
    unsigned short* pk = (unsigned short*)&pkv;
#pragma unroll
    for (int j = 0; j < 8; ++j) {
      const int r = g * 8 + j;
      float uu  = bf2f(ub[(size_t)(b0 + r) * OUTF + o]);
      float ysm = __expf(uu - smax[r]) * sinv[r];
      float yn  = (o == sarg[r]) ? ysm : -ysm;
      sacc += yn * uu;
      pk[j] = f2bf(yn);
    }
    *(uint4*)&tile[t][g * 8] = pkv;
  }
  s_part[(size_t)blockIdx.y * OUTF + o] = sacc;
  __syncthreads();
#pragma unroll
  for (int it = 0; it < 8; ++it) {
    const int row = it * 32 + (t >> 3);
    const int seg = (t & 7) * 8;  // halves
    uint4 vv = *(const uint4*)&tile[row][seg];
    *(uint4*)&ynT[(size_t)(o0 + row) * BATCH + b0 + seg] = vv;
  }
}

// ---------------------------------------------------------------------------
// Kernel 6: block id -> o = (id&7)<<7 | id>>3  (XCD-local spart lines)
//   sb = (sum_{k<128} s_part[k][o]) / B
//   out[o][i] = rate[o] * (sum_z bf16 Cpart[z][o][i]/B - sb*W[o][i])
// ---------------------------------------------------------------------------
__global__ __launch_bounds__(256) void k_final(
    const unsigned short* __restrict__ Cp, const float* __restrict__ W,
    const float* __restrict__ s_part, const float* __restrict__ rate,
    float* __restrict__ out) {
  __shared__ float sred[128];
  const int t  = threadIdx.x;
  const int id = blockIdx.x;
  const int o  = ((id & 7) << 7) | (id >> 3);
  if (t < 128) sred[t] = s_part[(size_t)t * OUTF + o];
  __syncthreads();
  for (int s2 = 64; s2 > 0; s2 >>= 1) {
    if (t < s2) sred[t] += sred[t + s2];
    __syncthreads();
  }
  const float sb = sred[0] * INV_B;
  const float rt = rate[o];
  const int i0 = t * 4;
  float cx = 0, cy = 0, cz = 0, cw = 0;
#pragma unroll
  for (int z = 0; z < SPLITZ; ++z) {
    ushort4 h = *(const ushort4*)&Cp[(size_t)z * (1024u * 1024u) +
                                     (size_t)o * INF_ + i0];
    cx += bf2f(h.x); cy += bf2f(h.y); cz += bf2f(h.z); cw += bf2f(h.w);
  }
  float4 w = *(const float4*)&W[(size_t)o * INF_ + i0];
  float4 r;
  r.x = rt * (cx * INV_B - sb * w.x);
  r.y = rt * (cy * INV_B - sb * w.y);
  r.z = rt * (cz * INV_B - sb * w.z);
  r.w = rt * (cw * INV_B - sb * w.w);
  *(float4*)&out[(size_t)o * INF_ + i0] = r;
}

// ---------------------------------------------------------------------------
// Workspace layout (bytes):
//   0        : ub bf16 [8192][1024] 16 MB (GEMM1 out; dead after k_yn)
//              REUSED as GEMM2 bf16 Cpart[8][1024][1024] = 16 MB
//   16777216 : xb  bf16 16 MB (dead after GEMM1)
//   33554432 : xT  bf16 [1024][8192] 16 MB
//   50331648 : ynT bf16 [1024][8192] 16 MB
//   67108864 : Wb  bf16 2 MB
//   69206016 : rate fp32 [1024] 4 KB
//   69210112 : s_part fp32 [128][1024] 512 KB
//   69734400 : rowmax fp32 [8192] 32 KB
//   69767168 : rowinv fp32 [8192] 32 KB
//   69799936 : rowarg int  [8192] 32 KB
//   total ~69.9 MB
// ---------------------------------------------------------------------------
extern "C" void kernel_launch(void* const* d_in, const int* in_sizes, int n_in,
                              void* d_out, int out_size, void* d_ws, size_t ws_size,
                              hipStream_t stream) {
  const float* x    = (const float*)d_in[0];
  const float* W    = (const float*)d_in[1];
  const float* bias = (const float*)d_in[2];
  float* out = (float*)d_out;
  char* ws = (char*)d_ws;

  unsigned short* ub    = (unsigned short*)(ws + 0);
  unsigned short* xb    = (unsigned short*)(ws + 16777216);
  unsigned short* xT    = (unsigned short*)(ws + 33554432);
  unsigned short* ynT   = (unsigned short*)(ws + 50331648);
  unsigned short* Wb    = (unsigned short*)(ws + 67108864);
  float*          rate  = (float*)(ws + 69206016);
  float*          spart = (float*)(ws + 69210112);
  float*          rmax  = (float*)(ws + 69734400);
  float*          rinv  = (float*)(ws + 69767168);
  int*            rarg  = (int*)  (ws + 69799936);

  k_convert<<<dim3(3072), 256, 0, stream>>>(x, xb, xT, W, Wb, rate);
  // GEMM1: u[b][o] = x@W.T + b (bf16 out), M=8192 N=1024 K=1024, XCD-grouped
  k_gemm<<<dim3(512), 256, 0, stream>>>(xb, Wb, 1024, 1024, 1024,
                                        ub, 1024, bias, 0);
  // high-occupancy stats (2048 blocks) + exact-argmax repair
  k_row_stats<<<dim3(2048), 256, 0, stream>>>(ub, x, W, rmax, rinv, rarg);
  // streaming yn / ynT / spart
  k_yn<<<dim3(4, 128), 256, 0, stream>>>(ub, rmax, rinv, rarg, ynT, spart);
  // GEMM2: C[o][i] = yn.T@x, M=1024 N=1024 K=8192, split-K x8 kChunk=1024
  // (bf16 partials overwrite ub, dead)
  k_gemm<<<dim3(512), 256, 0, stream>>>(ynT, xT, 8192, 8192, 1024,
                                        ws, 1024, nullptr, 1);
  k_final<<<dim3(1024), 256, 0, stream>>>((const unsigned short*)ws, W, spart,
                                          rate, out);
}

// Round 9
// 150.719 us; speedup vs baseline: 1.0885x; 1.0190x over previous
//
#include <hip/hip_runtime.h>

// Problem constants
#define BATCH 8192
#define INF_  1024   // IN
#define OUTF  1024   // OUT
#define INV_B (1.0f/8192.0f)
#define RATE_C 1e-3f
#define SPLITZ 8     // GEMM2 split-K factor (bf16 partials)

typedef __bf16 bf16x8 __attribute__((ext_vector_type(8)));
typedef float  f32x4  __attribute__((ext_vector_type(4)));
typedef float  f32x16 __attribute__((ext_vector_type(16)));
typedef const __attribute__((address_space(1))) unsigned int* gas_t;
typedef __attribute__((address_space(3))) unsigned int* las_t;

// fp32 -> bf16 round-to-nearest-even
static __device__ __forceinline__ unsigned short f2bf(float f) {
  unsigned int u = __float_as_uint(f);
  u += 0x7fffu + ((u >> 16) & 1u);
  return (unsigned short)(u >> 16);
}
static __device__ __forceinline__ float bf2f(unsigned short h) {
  return __uint_as_float(((unsigned int)h) << 16);
}

// ---------------------------------------------------------------------------
// Kernel 1 (merged): blocks [0,2048): x -> xb (bf16) + xT (bf16, transposed)
//                    blocks [2048,3072): W row -> Wb + rate[o]
// ---------------------------------------------------------------------------
__global__ __launch_bounds__(256) void k_convert(
    const float* __restrict__ x, unsigned short* __restrict__ xb,
    unsigned short* __restrict__ xT, const float* __restrict__ W,
    unsigned short* __restrict__ Wb, float* __restrict__ rate) {
  const int t = threadIdx.x;
  if (blockIdx.x >= 2048) {
    __shared__ float red[256];
    const int o = blockIdx.x - 2048;
    float4 v = *(const float4*)&W[(size_t)o * INF_ + t * 4];
    ushort4 h;
    h.x = f2bf(v.x); h.y = f2bf(v.y); h.z = f2bf(v.z); h.w = f2bf(v.w);
    *(ushort4*)&Wb[(size_t)o * INF_ + t * 4] = h;
    red[t] = v.x * v.x + v.y * v.y + v.z * v.z + v.w * v.w;
    __syncthreads();
    for (int s = 128; s > 0; s >>= 1) {
      if (t < s) red[t] += red[t + s];
      __syncthreads();
    }
    if (t == 0) {
      float nrm = sqrtf(red[0]);
      rate[o] = RATE_C * sqrtf(fabsf(1.0f - nrm));
    }
    return;
  }
  // ---- x convert + transpose (64x64 tile), packed-u32 LDS ----
  __shared__ unsigned int t32[64][33];
  const int bx = blockIdx.x & 15;
  const int by = blockIdx.x >> 4;
  const int r0 = by * 64;
  const int c0 = bx * 64;
  const int m = t & 15;
  const int q = t >> 4;
#pragma unroll
  for (int p = 0; p < 2; ++p) {
    const int r2 = p * 16 + q;
    const int b  = r0 + 2 * r2;
    float4 v0 = *(const float4*)&x[(size_t)b * INF_ + c0 + 4 * m];
    float4 v1 = *(const float4*)&x[(size_t)(b + 1) * INF_ + c0 + 4 * m];
    ushort4 h0, h1;
    h0.x = f2bf(v0.x); h0.y = f2bf(v0.y); h0.z = f2bf(v0.z); h0.w = f2bf(v0.w);
    h1.x = f2bf(v1.x); h1.y = f2bf(v1.y); h1.z = f2bf(v1.z); h1.w = f2bf(v1.w);
    *(ushort4*)&xb[(size_t)b * INF_ + c0 + 4 * m] = h0;
    *(ushort4*)&xb[(size_t)(b + 1) * INF_ + c0 + 4 * m] = h1;
    t32[4 * m + 0][r2] = (unsigned int)h0.x | ((unsigned int)h1.x << 16);
    t32[4 * m + 1][r2] = (unsigned int)h0.y | ((unsigned int)h1.y << 16);
    t32[4 * m + 2][r2] = (unsigned int)h0.z | ((unsigned int)h1.z << 16);
    t32[4 * m + 3][r2] = (unsigned int)h0.w | ((unsigned int)h1.w << 16);
  }
  __syncthreads();
  const int c  = t >> 2;
  const int sg = t & 3;
  unsigned int vb[8];
#pragma unroll
  for (int k = 0; k < 8; ++k) vb[k] = t32[c][sg * 8 + k];
  unsigned short* dst = &xT[(size_t)(c0 + c) * BATCH + r0 + sg * 16];
  *(uint4*)&dst[0] = make_uint4(vb[0], vb[1], vb[2], vb[3]);
  *(uint4*)&dst[8] = make_uint4(vb[4], vb[5], vb[6], vb[7]);
}

// ---------------------------------------------------------------------------
// Kernel 2/5: NT bf16 GEMM, 128x128 tile, BK=64, global_load_lds width=16,
// XOR chunk swizzle, 32x32x16 MFMA (wave tile 64x64 = 2x2).
//
// DOUBLE-BUFFERED staging with prefetch-after-barrier (one barrier/iter):
//   __syncthreads()  -> drains this tile's DMAs + fences last compute
//   issue DMAs for tile k+1 into the other buffer (overlaps compute)
//   compute tile k
// This hides the global->LDS latency behind the MFMA/ds_read phase instead
// of exposing it in the barrier's vmcnt(0) drain every iteration.
// LDS: 2 x 32 KB staging (epilogue reuses buffer 0; pitch 132 -> coalesced
// full-sector bf16 stores).
// XCD-aware 1-D grids:
//   mode 0 (GEMM1, 512 blocks): by%8==id%8 -> XCD-local A strips + full Wb.
//   mode 1 (GEMM2, 512 blocks): bz=id&7 -> XCD owns one K=1024 slice.
// ---------------------------------------------------------------------------
__global__ __launch_bounds__(256, 2) void k_gemm(
    const unsigned short* __restrict__ A, const unsigned short* __restrict__ B,
    int lda, int ldb, int kChunk, void* __restrict__ C, int ldc,
    const float* __restrict__ bias, int mode) {
  __shared__ unsigned short smem[2][16384];  // [buf][ As 128x64 | Bs 128x64 ]
  const int t  = threadIdx.x;
  const int id = blockIdx.x;
  int bx, by, bz;
  if (mode == 0) {
    by = (id & 7) | ((id >> 6) << 3);
    bx = (id >> 3) & 7;
    bz = 0;
  } else {
    bz = id & 7;
    by = (id >> 3) & 7;
    bx = (id >> 6) & 7;
  }
  const int m0   = by * 128;
  const int n0   = bx * 128;
  const int k0   = bz * kChunk;
  const int lane = t & 63;
  const int wave = t >> 6;
  const int sr   = lane >> 3;
  const int scx  = ((lane & 7) ^ sr) * 8;
  const int wm   = (wave >> 1) * 64;
  const int wn   = (wave & 1) * 64;
  const int fm   = lane & 31;           // row within 32-tile
  const int fh   = lane >> 5;           // half-wave: k-offset selector

  f32x16 acc[2][2] = {};

  const int ldsRow0 = wave * 8;
  const size_t gArow = (size_t)(m0 + ldsRow0 + sr) * lda + scx;
  const size_t gBrow = (size_t)(n0 + ldsRow0 + sr) * ldb + scx;

  // prologue: stage tile 0 into buffer 0
#pragma unroll
  for (int j = 0; j < 4; ++j) {
    __builtin_amdgcn_global_load_lds(
        (gas_t)&A[gArow + (size_t)j * 32 * lda + k0],
        (las_t)&smem[0][(ldsRow0 + j * 32) * 64], 16, 0, 0);
    __builtin_amdgcn_global_load_lds(
        (gas_t)&B[gBrow + (size_t)j * 32 * ldb + k0],
        (las_t)&smem[0][8192 + (ldsRow0 + j * 32) * 64], 16, 0, 0);
  }

  for (int ks = 0; ks < kChunk; ks += 64) {
    const int buf = (ks >> 6) & 1;
    __syncthreads();  // drains buf's DMAs; fences last compute on buf^1
    if (ks + 64 < kChunk) {
      const int kn = k0 + ks + 64;
#pragma unroll
      for (int j = 0; j < 4; ++j) {
        __builtin_amdgcn_global_load_lds(
            (gas_t)&A[gArow + (size_t)j * 32 * lda + kn],
            (las_t)&smem[buf ^ 1][(ldsRow0 + j * 32) * 64], 16, 0, 0);
        __builtin_amdgcn_global_load_lds(
            (gas_t)&B[gBrow + (size_t)j * 32 * ldb + kn],
            (las_t)&smem[buf ^ 1][8192 + (ldsRow0 + j * 32) * 64], 16, 0, 0);
      }
    }
    const unsigned short* As = smem[buf];
    const unsigned short* Bs = smem[buf] + 8192;
#pragma unroll
    for (int kk = 0; kk < 64; kk += 16) {
      const int ckk = (kk >> 3) + fh;          // 16-B chunk 0..7
      const int swz = (ckk ^ (lane & 7)) << 3; // halves
      bf16x8 af[2], bf[2];
#pragma unroll
      for (int i = 0; i < 2; ++i)
        af[i] = *(const bf16x8*)&As[(wm + i * 32 + fm) * 64 + swz];
#pragma unroll
      for (int i = 0; i < 2; ++i)
        bf[i] = *(const bf16x8*)&Bs[(wn + i * 32 + fm) * 64 + swz];
#pragma unroll
      for (int mt = 0; mt < 2; ++mt)
#pragma unroll
        for (int nt = 0; nt < 2; ++nt)
          acc[mt][nt] = __builtin_amdgcn_mfma_f32_32x32x16_bf16(
              af[mt], bf[nt], acc[mt][nt], 0, 0, 0);
    }
  }
  __syncthreads();  // all compute done before epilogue overwrites staging

  // Staged epilogue. C/D: col = lane&31, row = (r&3)+8*(r>>2)+4*(lane>>5)
  unsigned short* ep = &smem[0][0];  // 128 x 132 pitch = 33 KB < 64 KB
#pragma unroll
  for (int nt = 0; nt < 2; ++nt) {
    const int cc = wn + nt * 32 + fm;
    const float bv = (mode == 0) ? bias[n0 + cc] : 0.0f;
#pragma unroll
    for (int mt = 0; mt < 2; ++mt) {
#pragma unroll
      for (int r = 0; r < 16; ++r) {
        const int rr = wm + mt * 32 + (r & 3) + 8 * (r >> 2) + 4 * fh;
        ep[rr * 132 + cc] = f2bf(acc[mt][nt][r] + bv);
      }
    }
  }
  __syncthreads();
  unsigned short* Cb = (mode == 0)
      ? (unsigned short*)C
      : (unsigned short*)C + (size_t)bz * (1024u * 1024u);
#pragma unroll
  for (int i = 0; i < 8; ++i) {
    const int row = i * 16 + (t >> 4);
    const int ch  = (t & 15) * 8;
    const unsigned short* src = &ep[row * 132 + ch];
    unsigned short* dst = &Cb[(size_t)(m0 + row) * ldc + n0 + ch];
    *(uint2*)&dst[0] = *(const uint2*)&src[0];
    *(uint2*)&dst[4] = *(const uint2*)&src[4];
  }
}

// ---------------------------------------------------------------------------
// Kernel 3: per-row stats, wave-per-row (4 rows/block, 2048 blocks = 8/CU).
// bf16 u input; butterfly reductions; exact fp32 argmax repair (window 0.10).
// ---------------------------------------------------------------------------
__global__ __launch_bounds__(256) void k_row_stats(
    const unsigned short* __restrict__ ub, const float* __restrict__ x,
    const float* __restrict__ W, float* __restrict__ rowmax,
    float* __restrict__ rowinv, int* __restrict__ rowarg) {
  __shared__ int cands[4][32];
  __shared__ int cnt[4];
  const int lane = threadIdx.x & 63;
  const int wave = threadIdx.x >> 6;
  const int b    = blockIdx.x * 4 + wave;
  const int oBase = lane * 16;

  float a[16];
  {
    uint4 q0 = *(const uint4*)&ub[(size_t)b * OUTF + oBase];
    uint4 q1 = *(const uint4*)&ub[(size_t)b * OUTF + oBase + 8];
    const unsigned int* qa = (const unsigned int*)&q0;
    const unsigned int* qb = (const unsigned int*)&q1;
#pragma unroll
    for (int c = 0; c < 4; ++c) {
      a[2 * c]         = __uint_as_float(qa[c] << 16);
      a[2 * c + 1]     = __uint_as_float(qa[c] & 0xffff0000u);
      a[8 + 2 * c]     = __uint_as_float(qb[c] << 16);
      a[8 + 2 * c + 1] = __uint_as_float(qb[c] & 0xffff0000u);
    }
  }
  float mv = a[0]; int mi = oBase;
#pragma unroll
  for (int j = 1; j < 16; ++j)
    if (a[j] > mv) { mv = a[j]; mi = oBase + j; }
#pragma unroll
  for (int off = 1; off < 64; off <<= 1) {
    float ov = __shfl_xor(mv, off);
    int   oi = __shfl_xor(mi, off);
    if (ov > mv || (ov == mv && oi < mi)) { mv = ov; mi = oi; }
  }
  const float M = mv;
  float se = 0.0f;
#pragma unroll
  for (int j = 0; j < 16; ++j) se += __expf(a[j] - M);
#pragma unroll
  for (int off = 1; off < 64; off <<= 1) se += __shfl_xor(se, off);

  const float thr = M - 0.10f;
  unsigned int cflags = 0;
  int ccount = 0;
#pragma unroll
  for (int j = 0; j < 16; ++j)
    if (a[j] >= thr) { cflags |= (1u << j); ++ccount; }
  int tot = ccount;
#pragma unroll
  for (int off = 1; off < 64; off <<= 1) tot += __shfl_xor(tot, off);

  int best = mi;
  if (tot > 1) {
    if (lane == 0) cnt[wave] = 0;
    for (int j = 0; j < 16; ++j)
      if (cflags & (1u << j)) {
        int p = atomicAdd(&cnt[wave], 1);
        if (p < 32) cands[wave][p] = oBase + j;
      }
    int nc = cnt[wave]; if (nc > 32) nc = 32;
    float xr[16];
    const float* xp = &x[(size_t)b * INF_ + oBase];
#pragma unroll
    for (int j = 0; j < 16; j += 4) {
      float4 v = *(const float4*)&xp[j];
      xr[j] = v.x; xr[j + 1] = v.y; xr[j + 2] = v.z; xr[j + 3] = v.w;
    }
    float bv = -3.4e38f; int bi = 0x7fffffff;
    for (int c = 0; c < nc; ++c) {
      const int o = cands[wave][c];
      const float* wp = &W[(size_t)o * INF_ + oBase];
      float d = 0.0f;
#pragma unroll
      for (int j = 0; j < 16; j += 4) {
        float4 v = *(const float4*)&wp[j];
        d += xr[j] * v.x + xr[j + 1] * v.y + xr[j + 2] * v.z +
             xr[j + 3] * v.w;
      }
#pragma unroll
      for (int off = 1; off < 64; off <<= 1) d += __shfl_xor(d, off);
      if (d > bv || (d == bv && o < bi)) { bv = d; bi = o; }
    }
    best = bi;
  }
  if (lane == 0) {
    rowmax[b] = M;
    rowinv[b] = 1.0f / se;
    rowarg[b] = best;
  }
}

// ---------------------------------------------------------------------------
// Kernel 4: yn = negate_non_maximal(softmax(u)) from bf16 u; write ynT
// (bf16 [OUT][B], transposed via LDS) and per-block spart[by][o] = sum yn*u.
// ---------------------------------------------------------------------------
__global__ __launch_bounds__(256) void k_yn(
    const unsigned short* __restrict__ ub, const float* __restrict__ rowmax,
    const float* __restrict__ rowinv, const int* __restrict__ rowarg,
    unsigned short* __restrict__ ynT, float* __restrict__ s_part) {
  __shared__ unsigned short tile[256][72];
  __shared__ float smax[64], sinv[64];
  __shared__ int   sarg[64];
  const int t  = threadIdx.x;
  const int o0 = blockIdx.x * 256;
  const int b0 = blockIdx.y * 64;
  if (t < 64) {
    smax[t] = rowmax[b0 + t];
    sinv[t] = rowinv[b0 + t];
    sarg[t] = rowarg[b0 + t];
  }
  __syncthreads();
  const int o = o0 + t;
  float sacc = 0.0f;
#pragma unroll
  for (int g = 0; g < 8; ++g) {
    uint4 pkv;
    unsigned short* pk = (unsigned short*)&pkv;
#pragma unroll
    for (int j = 0; j < 8; ++j) {
      const int r = g * 8 + j;
      float uu  = bf2f(ub[(size_t)(b0 + r) * OUTF + o]);
      float ysm = __expf(uu - smax[r]) * sinv[r];
      float yn  = (o == sarg[r]) ? ysm : -ysm;
      sacc += yn * uu;
      pk[j] = f2bf(yn);
    }
    *(uint4*)&tile[t][g * 8] = pkv;
  }
  s_part[(size_t)blockIdx.y * OUTF + o] = sacc;
  __syncthreads();
#pragma unroll
  for (int it = 0; it < 8; ++it) {
    const int row = it * 32 + (t >> 3);
    const int seg = (t & 7) * 8;  // halves
    uint4 vv = *(const uint4*)&tile[row][seg];
    *(uint4*)&ynT[(size_t)(o0 + row) * BATCH + b0 + seg] = vv;
  }
}

// ---------------------------------------------------------------------------
// Kernel 6: block id -> o = (id&7)<<7 | id>>3  (XCD-local spart lines)
//   sb = (sum_{k<128} s_part[k][o]) / B
//   out[o][i] = rate[o] * (sum_z bf16 Cpart[z][o][i]/B - sb*W[o][i])
// ---------------------------------------------------------------------------
__global__ __launch_bounds__(256) void k_final(
    const unsigned short* __restrict__ Cp, const float* __restrict__ W,
    const float* __restrict__ s_part, const float* __restrict__ rate,
    float* __restrict__ out) {
  __shared__ float sred[128];
  const int t  = threadIdx.x;
  const int id = blockIdx.x;
  const int o  = ((id & 7) << 7) | (id >> 3);
  if (t < 128) sred[t] = s_part[(size_t)t * OUTF + o];
  __syncthreads();
  for (int s2 = 64; s2 > 0; s2 >>= 1) {
    if (t < s2) sred[t] += sred[t + s2];
    __syncthreads();
  }
  const float sb = sred[0] * INV_B;
  const float rt = rate[o];
  const int i0 = t * 4;
  float cx = 0, cy = 0, cz = 0, cw = 0;
#pragma unroll
  for (int z = 0; z < SPLITZ; ++z) {
    ushort4 h = *(const ushort4*)&Cp[(size_t)z * (1024u * 1024u) +
                                     (size_t)o * INF_ + i0];
    cx += bf2f(h.x); cy += bf2f(h.y); cz += bf2f(h.z); cw += bf2f(h.w);
  }
  float4 w = *(const float4*)&W[(size_t)o * INF_ + i0];
  float4 r;
  r.x = rt * (cx * INV_B - sb * w.x);
  r.y = rt * (cy * INV_B - sb * w.y);
  r.z = rt * (cz * INV_B - sb * w.z);
  r.w = rt * (cw * INV_B - sb * w.w);
  *(float4*)&out[(size_t)o * INF_ + i0] = r;
}

// ---------------------------------------------------------------------------
// Workspace layout (bytes):
//   0        : ub bf16 [8192][1024] 16 MB (GEMM1 out; dead after k_yn)
//              REUSED as GEMM2 bf16 Cpart[8][1024][1024] = 16 MB
//   16777216 : xb  bf16 16 MB (dead after GEMM1)
//   33554432 : xT  bf16 [1024][8192] 16 MB
//   50331648 : ynT bf16 [1024][8192] 16 MB
//   67108864 : Wb  bf16 2 MB
//   69206016 : rate fp32 [1024] 4 KB
//   69210112 : s_part fp32 [128][1024] 512 KB
//   69734400 : rowmax fp32 [8192] 32 KB
//   69767168 : rowinv fp32 [8192] 32 KB
//   69799936 : rowarg int  [8192] 32 KB
//   total ~69.9 MB
// ---------------------------------------------------------------------------
extern "C" void kernel_launch(void* const* d_in, const int* in_sizes, int n_in,
                              void* d_out, int out_size, void* d_ws, size_t ws_size,
                              hipStream_t stream) {
  const float* x    = (const float*)d_in[0];
  const float* W    = (const float*)d_in[1];
  const float* bias = (const float*)d_in[2];
  float* out = (float*)d_out;
  char* ws = (char*)d_ws;

  unsigned short* ub    = (unsigned short*)(ws + 0);
  unsigned short* xb    = (unsigned short*)(ws + 16777216);
  unsigned short* xT    = (unsigned short*)(ws + 33554432);
  unsigned short* ynT   = (unsigned short*)(ws + 50331648);
  unsigned short* Wb    = (unsigned short*)(ws + 67108864);
  float*          rate  = (float*)(ws + 69206016);
  float*          spart = (float*)(ws + 69210112);
  float*          rmax  = (float*)(ws + 69734400);
  float*          rinv  = (float*)(ws + 69767168);
  int*            rarg  = (int*)  (ws + 69799936);

  k_convert<<<dim3(3072), 256, 0, stream>>>(x, xb, xT, W, Wb, rate);
  // GEMM1: u[b][o] = x@W.T + b (bf16 out), M=8192 N=1024 K=1024, XCD-grouped
  k_gemm<<<dim3(512), 256, 0, stream>>>(xb, Wb, 1024, 1024, 1024,
                                        ub, 1024, bias, 0);
  // high-occupancy stats (2048 blocks) + exact-argmax repair
  k_row_stats<<<dim3(2048), 256, 0, stream>>>(ub, x, W, rmax, rinv, rarg);
  // streaming yn / ynT / spart
  k_yn<<<dim3(4, 128), 256, 0, stream>>>(ub, rmax, rinv, rarg, ynT, spart);
  // GEMM2: C[o][i] = yn.T@x, M=1024 N=1024 K=8192, split-K x8 kChunk=1024
  // (bf16 partials overwrite ub, dead)
  k_gemm<<<dim3(512), 256, 0, stream>>>(ynT, xT, 8192, 8192, 1024,
                                        ws, 1024, nullptr, 1);
  k_final<<<dim3(1024), 256, 0, stream>>>((const unsigned short*)ws, W, spart,
                                          rate, out);
}